// Round 7
// baseline (2552.989 us; speedup 1.0000x reference)
//
#include <hip/hip_runtime.h>

typedef unsigned int u32;
typedef unsigned long long u64;

#define Bc 256
#define Tc 325
#define NSc 39
#define COc 64
#define NCc 20
#define ESc 117
#define ETc 648

// workspace layout in 4-byte units
#define WS_ROFF_S 0        // 40 ints
#define WS_EDGE_S 64       // 117 int2 (234 w)
#define WS_DINV_S 304      // 39 f
#define WS_ROFF_T 352      // 326 ints
#define WS_EDGE_T 680      // 648 int2 (1296 w)
#define WS_DINV_T 1976     // 325 f
#define WS_W1T    2304     // 49920 f  (fc1_w transposed [20][2496])
#define WS_W2T    52224    // 416000 f (tfc1_w transposed [20][20800])

// ---------------- prep: CSR (by dst, interleaved {src, nrm}) ----------------
__global__ void prep_graph(const int* __restrict__ eiS, const int* __restrict__ eiT,
                           int* __restrict__ wsI, float* __restrict__ wsF) {
  const int which = blockIdx.x;
  const int* ei = which ? eiT : eiS;
  const int nE = which ? ETc : ESc;
  const int nN = which ? Tc : NSc;
  int* roff = wsI + (which ? WS_ROFF_T : WS_ROFF_S);
  int2* edge = (int2*)(wsI + (which ? WS_EDGE_T : WS_EDGE_S));
  float* dinv = wsF + (which ? WS_DINV_T : WS_DINV_S);
  const int* src = ei;
  const int* dst = ei + nE;
  for (int n = threadIdx.x; n < nN; n += blockDim.x) {
    int deg = 0, before = 0;
    for (int e = 0; e < nE; ++e) { deg += (dst[e] == n); before += (dst[e] < n); }
    roff[n] = before;
    if (n == nN - 1) roff[nN] = before + deg;
    dinv[n] = (deg > 0) ? (1.0f / sqrtf((float)deg)) : 0.0f;
  }
  __syncthreads();
  for (int n = threadIdx.x; n < nN; n += blockDim.x) {
    int cur = roff[n];
    float dn = dinv[n];
    for (int e = 0; e < nE; ++e) {
      if (dst[e] == n) {
        edge[cur] = make_int2(src[e], __float_as_int(dinv[src[e]] * dn));
        ++cur;
      }
    }
  }
}

// ---------------- prep: transpose both fc weights ----------------
__global__ void prep_w(const float* __restrict__ w1, float* __restrict__ w1T,
                       const float* __restrict__ w2, float* __restrict__ w2T) {
  int i = blockIdx.x * 256 + threadIdx.x;
  if (i < NCc * Tc * COc) {
    int j = i / (Tc * COc);
    int p = i - j * (Tc * COc);
    w2T[i] = w2[p * NCc + j];
  }
  if (i < NCc * NSc * COc) {
    int j = i / (NSc * COc);
    int p = i - j * (NSc * COc);
    w1T[i] = w1[p * NCc + j];
  }
}

// ---------------- fused kernel: 1 batch per block ----------------
__global__ __launch_bounds__(1024) __attribute__((amdgpu_waves_per_eu(4, 4)))
void lif_fused(const float* __restrict__ data,
               const int* __restrict__ roffSg, const int2* __restrict__ edgeSg,
               const int* __restrict__ roffTg, const int2* __restrict__ edgeTg,
               const float* __restrict__ c1w, const float* __restrict__ c1b,
               const float* __restrict__ c2w, const float* __restrict__ c2b,
               const float* __restrict__ w1T, const float* __restrict__ f1b,
               const float* __restrict__ w2T, const float* __restrict__ tf1b,
               float* __restrict__ out)
{
  __shared__ __align__(16) float feats[6500];   // A: [39][16][8] / B: [325][20]
  __shared__ u32 spkT[40 * Tc * 2];             // 104000 B (row 39 = pad)
  __shared__ u32 spkA[8 * 40 * 2];              // 2560 B (i=39 = pad, zeroed)
  __shared__ float partbuf[1280];               // A: [8][16][5]=640 / C: [5][3][20][4]=1200
  __shared__ float outS_l[NCc];
  __shared__ int roffS[NSc + 1];
  __shared__ int2 edgeS[ESc];
  __shared__ int roffT[Tc + 1];
  __shared__ int2 edgeT[ETc];

  const int tid = threadIdx.x;
  const int lane = tid & 63;
  const int wv = tid >> 6;
  const int b = blockIdx.x;
  const int lhalf = lane >> 5;
  const int lbit = lane & 31;
  const float* dbase = data + (size_t)b * (2 * NSc * 2 * Tc);

  for (int i = tid; i < NSc + 1; i += 1024) roffS[i] = roffSg[i];
  for (int i = tid; i < ESc; i += 1024) edgeS[i] = edgeSg[i];
  for (int i = tid; i < Tc + 1; i += 1024) roffT[i] = roffTg[i];
  for (int i = tid; i < ETc; i += 1024) edgeT[i] = edgeTg[i];
  if (tid < 640) spkA[tid] = 0u;
  __syncthreads();

  // ============ Phase A: spatial conv + fc, fused per 8-t tile ============
  {
    float wc[16];
#pragma unroll
    for (int r = 0; r < 16; ++r) wc[r] = c1w[r * COc + lane];
    const float bcv = c1b[lane];
    float cm[3] = {0.0f, 0.0f, 0.0f};
    const int nq = (wv < 7) ? 3 : 2;

    // register-resident fc weights: wave = (jgA 4 groups of 5 j) x (iqA 4 quarters of 10 i)
    const int jgA = wv >> 2, iqA = wv & 3;
    float wfc[50];
#pragma unroll
    for (int ii = 0; ii < 10; ++ii) {
      int i = iqA * 10 + ii;
#pragma unroll
      for (int jj = 0; jj < 5; ++jj)
        wfc[ii * 5 + jj] = (i < NSc) ? w1T[(jgA * 5 + jj) * (NSc * COc) + i * COc + lane] : 0.0f;
    }
    const float bA0 = f1b[wv];
    const float bA1 = (wv < 4) ? f1b[16 + wv] : 0.0f;
    float hmA0 = 0.0f, hsA0 = 0.0f, hmA1 = 0.0f, hsA1 = 0.0f;
    const int g1 = wv / 5, q1 = wv % 5;                  // j1 = wv -> (jg, jj)
    const int g2 = (16 + wv) / 5, q2 = (16 + wv) % 5;    // j2 = 16+wv

#pragma unroll 1
    for (int tb = 0; tb < 41; ++tb) {
      const int t0 = tb * 8;
      // stage x: feats[n*128 + c*8 + dt]
#pragma unroll
      for (int it = 0; it < 2; ++it) {
        int idx = tid + it * 1024;
        if (idx < NSc * 32) {
          int n = idx >> 5, c = (idx >> 3) & 3, dt = idx & 7;
          int t = t0 + dt;
          float v = (t < Tc) ? dbase[(n + (c >> 1) * NSc) * 650 + (c & 1) * 325 + t] : 0.0f;
          feats[n * 128 + c * 8 + dt] = v;
        }
      }
      __syncthreads();
#pragma unroll
      for (int k = 1; k <= 3; ++k) {
#pragma unroll
        for (int it = 0; it < 2; ++it) {
          int idx = tid + it * 1024;
          if (idx < NSc * 32) {
            int n = idx >> 5, c = (idx >> 3) & 3, dt = idx & 7;
            float v = 0.0f;
            for (int e = roffS[n]; e < roffS[n + 1]; ++e) {
              int2 ed = edgeS[e];
              v = fmaf(__int_as_float(ed.y), feats[ed.x * 128 + ((k - 1) * 4 + c) * 8 + dt], v);
            }
            feats[n * 128 + (k * 4 + c) * 8 + dt] = v;
          }
        }
        __syncthreads();
      }
      // conv + LIF + ballot -> spkA
#pragma unroll
      for (int q = 0; q < 3; ++q) {
        if (q < nq) {
          int i = wv + 16 * q;
          float za[8];
#pragma unroll
          for (int dt = 0; dt < 8; ++dt) za[dt] = bcv;
#pragma unroll
          for (int r = 0; r < 16; ++r) {
            float4 fa = *(const float4*)&feats[i * 128 + r * 8];
            float4 fb = *(const float4*)&feats[i * 128 + r * 8 + 4];
            za[0] = fmaf(fa.x, wc[r], za[0]);
            za[1] = fmaf(fa.y, wc[r], za[1]);
            za[2] = fmaf(fa.z, wc[r], za[2]);
            za[3] = fmaf(fa.w, wc[r], za[3]);
            za[4] = fmaf(fb.x, wc[r], za[4]);
            za[5] = fmaf(fb.y, wc[r], za[5]);
            za[6] = fmaf(fb.z, wc[r], za[6]);
            za[7] = fmaf(fb.w, wc[r], za[7]);
          }
#pragma unroll
          for (int dt = 0; dt < 8; ++dt) {
            if (t0 + dt < Tc) {
              float old = cm[q];
              float m = (old * 0.2f) * ((old > 0.5f) ? 0.0f : 1.0f) + za[dt];
              cm[q] = m;
              u64 wd = __ballot(m > 0.5f);
              if (lane == 0) *(u64*)&spkA[(dt * 40 + i) * 2] = wd;
            }
          }
        }
      }
      __syncthreads();
      // fc: 2 rounds of 4 dt, register weights
#pragma unroll
      for (int r = 0; r < 2; ++r) {
        float ya[4][5];
#pragma unroll
        for (int ds = 0; ds < 4; ++ds)
#pragma unroll
          for (int jj = 0; jj < 5; ++jj) ya[ds][jj] = 0.0f;
#pragma unroll
        for (int ii = 0; ii < 10; ++ii) {
          int i = iqA * 10 + ii;     // i=39 reads zeroed pad, wfc=0
#pragma unroll
          for (int ds = 0; ds < 4; ++ds) {
            u32 wb = spkA[((r * 4 + ds) * 40 + i) * 2 + lhalf];
            float g = (float)((wb >> lbit) & 1u);
#pragma unroll
            for (int jj = 0; jj < 5; ++jj)
              ya[ds][jj] = fmaf(g, wfc[ii * 5 + jj], ya[ds][jj]);
          }
        }
#pragma unroll
        for (int off = 32; off >= 1; off >>= 1)
#pragma unroll
          for (int ds = 0; ds < 4; ++ds)
#pragma unroll
            for (int jj = 0; jj < 5; ++jj)
              ya[ds][jj] += __shfl_xor(ya[ds][jj], off, 64);
        if (lane == 0) {
#pragma unroll
          for (int ds = 0; ds < 4; ++ds)
#pragma unroll
            for (int jj = 0; jj < 5; ++jj)
              partbuf[((r * 4 + ds) * 16 + wv) * 5 + jj] = ya[ds][jj];
        }
      }
      __syncthreads();
      // h-LIF: wave wv -> j=wv (and 16+wv for wv<4)
#pragma unroll
      for (int dtt = 0; dtt < 8; ++dtt) {
        int t = t0 + dtt;
        if (t < Tc) {
          float y = partbuf[(dtt * 16 + g1 * 4 + 0) * 5 + q1]
                  + partbuf[(dtt * 16 + g1 * 4 + 1) * 5 + q1]
                  + partbuf[(dtt * 16 + g1 * 4 + 2) * 5 + q1]
                  + partbuf[(dtt * 16 + g1 * 4 + 3) * 5 + q1] + bA0;
          hmA0 = (hmA0 * 0.2f) * ((hmA0 > 0.5f) ? 0.0f : 1.0f) + y;
          hsA0 += (hmA0 > 0.5f) ? 1.0f : 0.0f;
          if (wv < 4) {
            float y2 = partbuf[(dtt * 16 + g2 * 4 + 0) * 5 + q2]
                     + partbuf[(dtt * 16 + g2 * 4 + 1) * 5 + q2]
                     + partbuf[(dtt * 16 + g2 * 4 + 2) * 5 + q2]
                     + partbuf[(dtt * 16 + g2 * 4 + 3) * 5 + q2] + bA1;
            hmA1 = (hmA1 * 0.2f) * ((hmA1 > 0.5f) ? 0.0f : 1.0f) + y2;
            hsA1 += (hmA1 > 0.5f) ? 1.0f : 0.0f;
          }
        }
      }
      __syncthreads();
    }
    if (lane == 0) {
      outS_l[wv] = hsA0 / (float)Tc;
      if (wv < 4) outS_l[16 + wv] = hsA1 / (float)Tc;
    }
  }
  __syncthreads();

  // ============ Phase B: temporal conv chain -> spike words spkT[s][i] ============
  {
    float wc[16];
#pragma unroll
    for (int r = 0; r < 16; ++r) wc[r] = c2w[r * COc + lane];
    const float bcv = c2b[lane];
    float tm[21];
#pragma unroll
    for (int q = 0; q < 21; ++q) tm[q] = 0.0f;
    const int nq = (wv < 5) ? 21 : 20;

#pragma unroll 1
    for (int s = 0; s < NSc; ++s) {
#pragma unroll
      for (int it = 0; it < 2; ++it) {
        int idx = tid + it * 1024;
        if (idx < Tc * 4) {
          int c = idx / Tc, t = idx - c * Tc;
          feats[t * 20 + c] = dbase[(s + (c >> 1) * NSc) * 650 + (c & 1) * 325 + t];
        }
      }
      __syncthreads();
#pragma unroll
      for (int k = 1; k <= 3; ++k) {
#pragma unroll
        for (int it = 0; it < 2; ++it) {
          int idx = tid + it * 1024;
          if (idx < Tc * 4) {
            int t = idx >> 2, c = idx & 3;
            float v = 0.0f;
            for (int e = roffT[t]; e < roffT[t + 1]; ++e) {
              int2 ed = edgeT[e];
              v = fmaf(__int_as_float(ed.y), feats[ed.x * 20 + (k - 1) * 4 + c], v);
            }
            feats[t * 20 + k * 4 + c] = v;
          }
        }
        __syncthreads();
      }
#pragma unroll
      for (int q = 0; q < 21; ++q) {
        if (q < nq) {
          int i = wv + 16 * q;
          float4 f0 = *(const float4*)&feats[i * 20 + 0];
          float4 f1 = *(const float4*)&feats[i * 20 + 4];
          float4 f2 = *(const float4*)&feats[i * 20 + 8];
          float4 f3 = *(const float4*)&feats[i * 20 + 12];
          float acc = bcv;
          acc = fmaf(f0.x, wc[0], acc);  acc = fmaf(f0.y, wc[1], acc);
          acc = fmaf(f0.z, wc[2], acc);  acc = fmaf(f0.w, wc[3], acc);
          acc = fmaf(f1.x, wc[4], acc);  acc = fmaf(f1.y, wc[5], acc);
          acc = fmaf(f1.z, wc[6], acc);  acc = fmaf(f1.w, wc[7], acc);
          acc = fmaf(f2.x, wc[8], acc);  acc = fmaf(f2.y, wc[9], acc);
          acc = fmaf(f2.z, wc[10], acc); acc = fmaf(f2.w, wc[11], acc);
          acc = fmaf(f3.x, wc[12], acc); acc = fmaf(f3.y, wc[13], acc);
          acc = fmaf(f3.z, wc[14], acc); acc = fmaf(f3.w, wc[15], acc);
          float old = tm[q];
          float m = (old * 0.2f) * ((old > 0.5f) ? 0.0f : 1.0f) + acc;
          tm[q] = m;
          u64 wd = __ballot(m > 0.5f);
          if (lane == 0) *(u64*)&spkT[(s * Tc + i) * 2] = wd;
        }
      }
      __syncthreads();
    }
  }

  // ============ Phase C: temporal fc, 2 passes over w2T ============
  {
    const int jgC = wv / 3;            // 0..4 (wv 0..14); wv 15 idle in GEMM
    const int iqC = wv % 3;
    const int j0C = jgC * 4;
    const int i0C = (iqC * Tc) / 3, i1C = ((iqC + 1) * Tc) / 3;
    const float* wp0 = w2T + (size_t)(j0C + 0) * (Tc * COc) + lane;
    const float* wp1 = w2T + (size_t)(j0C + 1) * (Tc * COc) + lane;
    const float* wp2 = w2T + (size_t)(j0C + 2) * (Tc * COc) + lane;
    const float* wp3 = w2T + (size_t)(j0C + 3) * (Tc * COc) + lane;
    const float bC0 = tf1b[wv < NCc ? wv : 0];
    const float bC1 = (wv < 4) ? tf1b[16 + wv] : 0.0f;
    const int gg1 = wv >> 2, qq1 = wv & 3;             // j1 = wv -> (j/4, j%4)
    const int gg2 = (16 + wv) >> 2, qq2 = (16 + wv) & 3;
    float hmC0 = 0.0f, hsC0 = 0.0f, hmC1 = 0.0f, hsC1 = 0.0f;

#pragma unroll 1
    for (int pass = 0; pass < 2; ++pass) {
      const int s0 = pass * 20;
      const int sn = pass ? 19 : 20;
      float ya[20][4];
#pragma unroll
      for (int s = 0; s < 20; ++s)
#pragma unroll
        for (int jj = 0; jj < 4; ++jj) ya[s][jj] = 0.0f;

      if (wv < 15) {
#pragma unroll 2
        for (int i = i0C; i < i1C; ++i) {
          float w0 = wp0[(size_t)i * COc];
          float w1 = wp1[(size_t)i * COc];
          float w2 = wp2[(size_t)i * COc];
          float w3 = wp3[(size_t)i * COc];
#pragma unroll
          for (int s = 0; s < 20; ++s) {
            u32 wb = spkT[((s0 + s) * Tc + i) * 2 + lhalf];
            float g = (float)((wb >> lbit) & 1u);
            ya[s][0] = fmaf(g, w0, ya[s][0]);
            ya[s][1] = fmaf(g, w1, ya[s][1]);
            ya[s][2] = fmaf(g, w2, ya[s][2]);
            ya[s][3] = fmaf(g, w3, ya[s][3]);
          }
        }
#pragma unroll
        for (int off = 32; off >= 1; off >>= 1)
#pragma unroll
          for (int s = 0; s < 20; ++s)
#pragma unroll
            for (int jj = 0; jj < 4; ++jj)
              ya[s][jj] += __shfl_xor(ya[s][jj], off, 64);
        if (lane == 0) {
#pragma unroll
          for (int s = 0; s < 20; ++s)
#pragma unroll
            for (int jj = 0; jj < 4; ++jj)
              partbuf[((jgC * 3 + iqC) * 20 + s) * 4 + jj] = ya[s][jj];
        }
      }
      __syncthreads();
      // h-LIF: wave wv -> j=wv (and 16+wv for wv<4)
#pragma unroll
      for (int s = 0; s < 20; ++s) {
        if (s < sn) {
          float y = partbuf[((gg1 * 3 + 0) * 20 + s) * 4 + qq1]
                  + partbuf[((gg1 * 3 + 1) * 20 + s) * 4 + qq1]
                  + partbuf[((gg1 * 3 + 2) * 20 + s) * 4 + qq1] + bC0;
          hmC0 = (hmC0 * 0.2f) * ((hmC0 > 0.5f) ? 0.0f : 1.0f) + y;
          hsC0 += (hmC0 > 0.5f) ? 1.0f : 0.0f;
          if (wv < 4) {
            float y2 = partbuf[((gg2 * 3 + 0) * 20 + s) * 4 + qq2]
                     + partbuf[((gg2 * 3 + 1) * 20 + s) * 4 + qq2]
                     + partbuf[((gg2 * 3 + 2) * 20 + s) * 4 + qq2] + bC1;
            hmC1 = (hmC1 * 0.2f) * ((hmC1 > 0.5f) ? 0.0f : 1.0f) + y2;
            hsC1 += (hmC1 > 0.5f) ? 1.0f : 0.0f;
          }
        }
      }
      __syncthreads();
    }
    if (lane == 0) {
      out[b * NCc + wv] = (outS_l[wv] + hsC0 / (float)NSc) * 0.5f;
      if (wv < 4)
        out[b * NCc + 16 + wv] = (outS_l[16 + wv] + hsC1 / (float)NSc) * 0.5f;
    }
  }
}

extern "C" void kernel_launch(void* const* d_in, const int* in_sizes, int n_in,
                              void* d_out, int out_size, void* d_ws, size_t ws_size,
                              hipStream_t stream) {
  const float* data = (const float*)d_in[0];
  const int*   eiS  = (const int*)d_in[1];
  const int*   eiT  = (const int*)d_in[2];
  const float* c1w  = (const float*)d_in[3];
  const float* c1b  = (const float*)d_in[4];
  const float* c2w  = (const float*)d_in[5];
  const float* c2b  = (const float*)d_in[6];
  const float* f1w  = (const float*)d_in[7];
  const float* f1b  = (const float*)d_in[8];
  const float* tf1w = (const float*)d_in[9];
  const float* tf1b = (const float*)d_in[10];
  float* out = (float*)d_out;
  int* wsI = (int*)d_ws;
  float* wsF = (float*)d_ws;

  prep_graph<<<2, 256, 0, stream>>>(eiS, eiT, wsI, wsF);
  prep_w<<<(NCc * Tc * COc + 255) / 256, 256, 0, stream>>>(f1w, wsF + WS_W1T,
                                                           tf1w, wsF + WS_W2T);
  lif_fused<<<Bc, 1024, 0, stream>>>(data,
                                     wsI + WS_ROFF_S, (const int2*)(wsI + WS_EDGE_S),
                                     wsI + WS_ROFF_T, (const int2*)(wsI + WS_EDGE_T),
                                     c1w, c1b, c2w, c2b,
                                     wsF + WS_W1T, f1b, wsF + WS_W2T, tf1b,
                                     out);
}

// Round 8
// 1869.743 us; speedup vs baseline: 1.3654x; 1.3654x over previous
//
#include <hip/hip_runtime.h>

typedef unsigned int u32;
typedef unsigned long long u64;

#define Bc 256
#define Tc 325
#define NSc 39
#define COc 64
#define NCc 20
#define ESc 117
#define ETc 648
#define CH 13          // s-chunk size (39 = 3*13, 325 = 25*13)

// workspace layout in 4-byte units
#define WS_ROFF_S 0        // 40 ints
#define WS_EDGE_S 64       // 117 int2 (234 w)
#define WS_DINV_S 304      // 39 f
#define WS_ROFF_T 352      // 326 ints
#define WS_EDGE_T 680      // 648 int2 (1296 w)
#define WS_DINV_T 1976     // 325 f
#define WS_W1T    2304     // 49920 f  (fc1_w transposed [20][2496])
#define WS_W2T    52224    // 416000 f (tfc1_w transposed [20][20800])

// ---------------- prep: CSR (by dst, interleaved {src, nrm}) ----------------
__global__ void prep_graph(const int* __restrict__ eiS, const int* __restrict__ eiT,
                           int* __restrict__ wsI, float* __restrict__ wsF) {
  const int which = blockIdx.x;
  const int* ei = which ? eiT : eiS;
  const int nE = which ? ETc : ESc;
  const int nN = which ? Tc : NSc;
  int* roff = wsI + (which ? WS_ROFF_T : WS_ROFF_S);
  int2* edge = (int2*)(wsI + (which ? WS_EDGE_T : WS_EDGE_S));
  float* dinv = wsF + (which ? WS_DINV_T : WS_DINV_S);
  const int* src = ei;
  const int* dst = ei + nE;
  for (int n = threadIdx.x; n < nN; n += blockDim.x) {
    int deg = 0, before = 0;
    for (int e = 0; e < nE; ++e) { deg += (dst[e] == n); before += (dst[e] < n); }
    roff[n] = before;
    if (n == nN - 1) roff[nN] = before + deg;
    dinv[n] = (deg > 0) ? (1.0f / sqrtf((float)deg)) : 0.0f;
  }
  __syncthreads();
  for (int n = threadIdx.x; n < nN; n += blockDim.x) {
    int cur = roff[n];
    float dn = dinv[n];
    for (int e = 0; e < nE; ++e) {
      if (dst[e] == n) {
        edge[cur] = make_int2(src[e], __float_as_int(dinv[src[e]] * dn));
        ++cur;
      }
    }
  }
}

// ---------------- prep: transpose both fc weights ----------------
__global__ void prep_w(const float* __restrict__ w1, float* __restrict__ w1T,
                       const float* __restrict__ w2, float* __restrict__ w2T) {
  int i = blockIdx.x * 256 + threadIdx.x;
  if (i < NCc * Tc * COc) {
    int j = i / (Tc * COc);
    int p = i - j * (Tc * COc);
    w2T[i] = w2[p * NCc + j];
  }
  if (i < NCc * NSc * COc) {
    int j = i / (NSc * COc);
    int p = i - j * (NSc * COc);
    w1T[i] = w1[p * NCc + j];
  }
}

// ---------------- fused kernel: 1 batch per block, 512 threads, <=~100 VGPR ----------------
__global__ __launch_bounds__(512) __attribute__((amdgpu_waves_per_eu(2, 2)))
void lif_fused(const float* __restrict__ data,
               const int* __restrict__ roffSg, const int2* __restrict__ edgeSg,
               const int* __restrict__ roffTg, const int2* __restrict__ edgeTg,
               const float* __restrict__ c1w, const float* __restrict__ c1b,
               const float* __restrict__ c2w, const float* __restrict__ c2b,
               const float* __restrict__ w1T, const float* __restrict__ f1b,
               const float* __restrict__ w2T, const float* __restrict__ tf1b,
               float* __restrict__ out)
{
  __shared__ u64 spk[NSc * Tc];                    // 101400 B: A=[t][39], B=[s][325]
  __shared__ __align__(16) float feats[Tc * 20];   // 26000 B: A uses [39][20], B [325][20]
  __shared__ float partials[4][2][CH][5];          // 2080 B
  __shared__ float outS_l[NCc];
  __shared__ int roffS[NSc + 1];
  __shared__ int2 edgeS[ESc];
  __shared__ int roffT[Tc + 1];
  __shared__ int2 edgeT[ETc];

  const int tid = threadIdx.x;
  const int lane = tid & 63;
  const int wv = tid >> 6;             // 0..7
  const int b = blockIdx.x;
  const int lhalf = lane >> 5;
  const int lbit = lane & 31;
  const float* dbase = data + (size_t)b * (2 * NSc * 2 * Tc);

  for (int i = tid; i < NSc + 1; i += 512) roffS[i] = roffSg[i];
  for (int i = tid; i < ESc; i += 512) edgeS[i] = edgeSg[i];
  for (int i = tid; i < Tc + 1; i += 512) roffT[i] = roffTg[i];
  for (int i = tid; i < ETc; i += 512) edgeT[i] = edgeTg[i];
  __syncthreads();

  // ============ A1: spatial conv chain -> spike words spk[t][i] ============
  {
    float wc[16];
#pragma unroll
    for (int r = 0; r < 16; ++r) wc[r] = c1w[r * COc + lane];
    const float bcv = c1b[lane];
    float cm[5] = {0, 0, 0, 0, 0};

#pragma unroll 1
    for (int t = 0; t < Tc; ++t) {
      // hops: wave c (<4) in-register per channel, lane = node, in-wave LDS chain
      if (wv < 4 && lane < NSc) {
        const int c = wv;
        float h = dbase[(lane + (c >> 1) * NSc) * 650 + (c & 1) * 325 + t];
        feats[lane * 20 + c] = h;
#pragma unroll
        for (int k = 1; k <= 3; ++k) {
          float v = 0.0f;
          for (int e = roffS[lane]; e < roffS[lane + 1]; ++e) {
            int2 ed = edgeS[e];
            v = fmaf(__int_as_float(ed.y), feats[ed.x * 20 + (k - 1) * 4 + c], v);
          }
          feats[lane * 20 + k * 4 + c] = v;
        }
      }
      __syncthreads();
      // conv + LIF + ballot (lane = out channel)
#pragma unroll
      for (int q = 0; q < 5; ++q) {
        int i = wv + 8 * q;
        if (i < NSc) {
          const float4* f4 = (const float4*)&feats[i * 20];
          float4 f0 = f4[0], f1 = f4[1], f2 = f4[2], f3 = f4[3];
          float acc = bcv;
          acc = fmaf(f0.x, wc[0], acc);  acc = fmaf(f0.y, wc[1], acc);
          acc = fmaf(f0.z, wc[2], acc);  acc = fmaf(f0.w, wc[3], acc);
          acc = fmaf(f1.x, wc[4], acc);  acc = fmaf(f1.y, wc[5], acc);
          acc = fmaf(f1.z, wc[6], acc);  acc = fmaf(f1.w, wc[7], acc);
          acc = fmaf(f2.x, wc[8], acc);  acc = fmaf(f2.y, wc[9], acc);
          acc = fmaf(f2.z, wc[10], acc); acc = fmaf(f2.w, wc[11], acc);
          acc = fmaf(f3.x, wc[12], acc); acc = fmaf(f3.y, wc[13], acc);
          acc = fmaf(f3.z, wc[14], acc); acc = fmaf(f3.w, wc[15], acc);
          float old = cm[q];
          float m = (old * 0.2f) * ((old > 0.5f) ? 0.0f : 1.0f) + acc;
          cm[q] = m;
          u64 wd = __ballot(m > 0.5f);
          if (lane == 0) spk[t * NSc + i] = wd;
        }
      }
      __syncthreads();
    }
  }

  // ============ A2: spatial fc binary GEMM + h-LIF, 25 chunks of 13 ============
  {
    const int jg = wv >> 1, ih = wv & 1;       // 4 j-groups x 2 i-halves
    const int iN = ih ? (NSc - 20) : 20;       // 20 / 19 nodes
    const int iBase = ih * 20;
    // owned outputs for LIF: j = wv, wv+8, wv+16(wv<4)
    const int ja = wv, jb = wv + 8, jc = wv + 16;
    const int jag = ja / 5, jaj = ja % 5;
    const int jbg = jb / 5, jbj = jb % 5;
    const int jcg = jc / 5, jcj = jc % 5;
    const float ba = f1b[ja], bb = f1b[jb];
    const float bcc = (wv < 4) ? f1b[jc] : 0.0f;
    float hma = 0.0f, hsa = 0.0f, hmb = 0.0f, hsb = 0.0f, hmc = 0.0f, hsc = 0.0f;

#pragma unroll 1
    for (int chn = 0; chn < 25; ++chn) {
      const int s0 = chn * CH;
      float ya[CH][5];
#pragma unroll
      for (int ds = 0; ds < CH; ++ds)
#pragma unroll
        for (int jj = 0; jj < 5; ++jj) ya[ds][jj] = 0.0f;

#pragma unroll 1
      for (int ii = 0; ii < iN; ++ii) {
        const int i = iBase + ii;
        const float* wp = w1T + i * COc + lane;
        float w0 = wp[(jg * 5 + 0) * (NSc * COc)];
        float w1 = wp[(jg * 5 + 1) * (NSc * COc)];
        float w2 = wp[(jg * 5 + 2) * (NSc * COc)];
        float w3 = wp[(jg * 5 + 3) * (NSc * COc)];
        float w4 = wp[(jg * 5 + 4) * (NSc * COc)];
#pragma unroll
        for (int ds = 0; ds < CH; ++ds) {
          u32 wrd = ((const u32*)spk)[((s0 + ds) * NSc + i) * 2 + lhalf];
          float g = (float)((wrd >> lbit) & 1u);
          ya[ds][0] = fmaf(g, w0, ya[ds][0]);
          ya[ds][1] = fmaf(g, w1, ya[ds][1]);
          ya[ds][2] = fmaf(g, w2, ya[ds][2]);
          ya[ds][3] = fmaf(g, w3, ya[ds][3]);
          ya[ds][4] = fmaf(g, w4, ya[ds][4]);
        }
      }
#pragma unroll
      for (int off = 32; off >= 1; off >>= 1)
#pragma unroll
        for (int ds = 0; ds < CH; ++ds)
#pragma unroll
          for (int jj = 0; jj < 5; ++jj)
            ya[ds][jj] += __shfl_xor(ya[ds][jj], off, 64);
      if (lane == 0) {
#pragma unroll
        for (int ds = 0; ds < CH; ++ds)
#pragma unroll
          for (int jj = 0; jj < 5; ++jj)
            partials[jg][ih][ds][jj] = ya[ds][jj];
      }
      __syncthreads();
      // h-LIF for owned j's
#pragma unroll
      for (int ds = 0; ds < CH; ++ds) {
        float y0 = partials[jag][0][ds][jaj] + partials[jag][1][ds][jaj] + ba;
        hma = (hma * 0.2f) * ((hma > 0.5f) ? 0.0f : 1.0f) + y0;
        hsa += (hma > 0.5f) ? 1.0f : 0.0f;
        float y1 = partials[jbg][0][ds][jbj] + partials[jbg][1][ds][jbj] + bb;
        hmb = (hmb * 0.2f) * ((hmb > 0.5f) ? 0.0f : 1.0f) + y1;
        hsb += (hmb > 0.5f) ? 1.0f : 0.0f;
        if (wv < 4) {
          float y2 = partials[jcg][0][ds][jcj] + partials[jcg][1][ds][jcj] + bcc;
          hmc = (hmc * 0.2f) * ((hmc > 0.5f) ? 0.0f : 1.0f) + y2;
          hsc += (hmc > 0.5f) ? 1.0f : 0.0f;
        }
      }
      __syncthreads();
    }
    if (lane == 0) {
      outS_l[ja] = hsa / (float)Tc;
      outS_l[jb] = hsb / (float)Tc;
      if (wv < 4) outS_l[jc] = hsc / (float)Tc;
    }
  }
  __syncthreads();

  // ============ B1: temporal conv chain -> spike words spk[s][i] ============
  {
    float wc[16];
#pragma unroll
    for (int r = 0; r < 16; ++r) wc[r] = c2w[r * COc + lane];
    const float bcv = c2b[lane];
    float tm[41];
#pragma unroll
    for (int q = 0; q < 41; ++q) tm[q] = 0.0f;

#pragma unroll 1
    for (int s = 0; s < NSc; ++s) {
      // stage x_s coalesced in t
#pragma unroll
      for (int it = 0; it < 3; ++it) {
        int idx = tid + 512 * it;
        if (idx < Tc * 4) {
          int c = idx / Tc, t = idx - c * Tc;
          feats[t * 20 + c] = dbase[(s + (c >> 1) * NSc) * 650 + (c & 1) * 325 + t];
        }
      }
      __syncthreads();
#pragma unroll
      for (int k = 1; k <= 3; ++k) {
#pragma unroll
        for (int it = 0; it < 3; ++it) {
          int idx = tid + 512 * it;
          if (idx < Tc * 4) {
            int t = idx >> 2, c = idx & 3;
            float v = 0.0f;
            for (int e = roffT[t]; e < roffT[t + 1]; ++e) {
              int2 ed = edgeT[e];
              v = fmaf(__int_as_float(ed.y), feats[ed.x * 20 + (k - 1) * 4 + c], v);
            }
            feats[t * 20 + k * 4 + c] = v;
          }
        }
        __syncthreads();
      }
#pragma unroll
      for (int q = 0; q < 41; ++q) {
        int i = wv + 8 * q;
        if (i < Tc) {
          const float4* f4 = (const float4*)&feats[i * 20];
          float4 f0 = f4[0], f1 = f4[1], f2 = f4[2], f3 = f4[3];
          float acc = bcv;
          acc = fmaf(f0.x, wc[0], acc);  acc = fmaf(f0.y, wc[1], acc);
          acc = fmaf(f0.z, wc[2], acc);  acc = fmaf(f0.w, wc[3], acc);
          acc = fmaf(f1.x, wc[4], acc);  acc = fmaf(f1.y, wc[5], acc);
          acc = fmaf(f1.z, wc[6], acc);  acc = fmaf(f1.w, wc[7], acc);
          acc = fmaf(f2.x, wc[8], acc);  acc = fmaf(f2.y, wc[9], acc);
          acc = fmaf(f2.z, wc[10], acc); acc = fmaf(f2.w, wc[11], acc);
          acc = fmaf(f3.x, wc[12], acc); acc = fmaf(f3.y, wc[13], acc);
          acc = fmaf(f3.z, wc[14], acc); acc = fmaf(f3.w, wc[15], acc);
          float old = tm[q];
          float m = (old * 0.2f) * ((old > 0.5f) ? 0.0f : 1.0f) + acc;
          tm[q] = m;
          u64 wd = __ballot(m > 0.5f);
          if (lane == 0) spk[s * Tc + i] = wd;
        }
      }
      __syncthreads();
    }
  }

  // ============ B2: temporal fc binary GEMM + h-LIF + combine, 3 chunks of 13 ============
  {
    const int jg = wv >> 1, ih = wv & 1;
    const int iN = ih ? (Tc - 163) : 163;      // 163 / 162
    const int iBase = ih * 163;
    const int ja = wv, jb = wv + 8, jc = wv + 16;
    const int jag = ja / 5, jaj = ja % 5;
    const int jbg = jb / 5, jbj = jb % 5;
    const int jcg = jc / 5, jcj = jc % 5;
    const float ba = tf1b[ja], bb = tf1b[jb];
    const float bcc = (wv < 4) ? tf1b[jc] : 0.0f;
    float hma = 0.0f, hsa = 0.0f, hmb = 0.0f, hsb = 0.0f, hmc = 0.0f, hsc = 0.0f;

#pragma unroll 1
    for (int chn = 0; chn < 3; ++chn) {
      const int s0 = chn * CH;
      float ya[CH][5];
#pragma unroll
      for (int ds = 0; ds < CH; ++ds)
#pragma unroll
        for (int jj = 0; jj < 5; ++jj) ya[ds][jj] = 0.0f;

#pragma unroll 1
      for (int ii = 0; ii < iN; ++ii) {
        const int i = iBase + ii;
        const float* wp = w2T + i * COc + lane;
        float w0 = wp[(size_t)(jg * 5 + 0) * (Tc * COc)];
        float w1 = wp[(size_t)(jg * 5 + 1) * (Tc * COc)];
        float w2 = wp[(size_t)(jg * 5 + 2) * (Tc * COc)];
        float w3 = wp[(size_t)(jg * 5 + 3) * (Tc * COc)];
        float w4 = wp[(size_t)(jg * 5 + 4) * (Tc * COc)];
#pragma unroll
        for (int ds = 0; ds < CH; ++ds) {
          u32 wrd = ((const u32*)spk)[((s0 + ds) * Tc + i) * 2 + lhalf];
          float g = (float)((wrd >> lbit) & 1u);
          ya[ds][0] = fmaf(g, w0, ya[ds][0]);
          ya[ds][1] = fmaf(g, w1, ya[ds][1]);
          ya[ds][2] = fmaf(g, w2, ya[ds][2]);
          ya[ds][3] = fmaf(g, w3, ya[ds][3]);
          ya[ds][4] = fmaf(g, w4, ya[ds][4]);
        }
      }
#pragma unroll
      for (int off = 32; off >= 1; off >>= 1)
#pragma unroll
        for (int ds = 0; ds < CH; ++ds)
#pragma unroll
          for (int jj = 0; jj < 5; ++jj)
            ya[ds][jj] += __shfl_xor(ya[ds][jj], off, 64);
      if (lane == 0) {
#pragma unroll
        for (int ds = 0; ds < CH; ++ds)
#pragma unroll
          for (int jj = 0; jj < 5; ++jj)
            partials[jg][ih][ds][jj] = ya[ds][jj];
      }
      __syncthreads();
#pragma unroll
      for (int ds = 0; ds < CH; ++ds) {
        float y0 = partials[jag][0][ds][jaj] + partials[jag][1][ds][jaj] + ba;
        hma = (hma * 0.2f) * ((hma > 0.5f) ? 0.0f : 1.0f) + y0;
        hsa += (hma > 0.5f) ? 1.0f : 0.0f;
        float y1 = partials[jbg][0][ds][jbj] + partials[jbg][1][ds][jbj] + bb;
        hmb = (hmb * 0.2f) * ((hmb > 0.5f) ? 0.0f : 1.0f) + y1;
        hsb += (hmb > 0.5f) ? 1.0f : 0.0f;
        if (wv < 4) {
          float y2 = partials[jcg][0][ds][jcj] + partials[jcg][1][ds][jcj] + bcc;
          hmc = (hmc * 0.2f) * ((hmc > 0.5f) ? 0.0f : 1.0f) + y2;
          hsc += (hmc > 0.5f) ? 1.0f : 0.0f;
        }
      }
      __syncthreads();
    }
    if (lane == 0) {
      out[b * NCc + ja] = (outS_l[ja] + hsa / (float)NSc) * 0.5f;
      out[b * NCc + jb] = (outS_l[jb] + hsb / (float)NSc) * 0.5f;
      if (wv < 4)
        out[b * NCc + jc] = (outS_l[jc] + hsc / (float)NSc) * 0.5f;
    }
  }
}

extern "C" void kernel_launch(void* const* d_in, const int* in_sizes, int n_in,
                              void* d_out, int out_size, void* d_ws, size_t ws_size,
                              hipStream_t stream) {
  const float* data = (const float*)d_in[0];
  const int*   eiS  = (const int*)d_in[1];
  const int*   eiT  = (const int*)d_in[2];
  const float* c1w  = (const float*)d_in[3];
  const float* c1b  = (const float*)d_in[4];
  const float* c2w  = (const float*)d_in[5];
  const float* c2b  = (const float*)d_in[6];
  const float* f1w  = (const float*)d_in[7];
  const float* f1b  = (const float*)d_in[8];
  const float* tf1w = (const float*)d_in[9];
  const float* tf1b = (const float*)d_in[10];
  float* out = (float*)d_out;
  int* wsI = (int*)d_ws;
  float* wsF = (float*)d_ws;

  prep_graph<<<2, 256, 0, stream>>>(eiS, eiT, wsI, wsF);
  prep_w<<<(NCc * Tc * COc + 255) / 256, 256, 0, stream>>>(f1w, wsF + WS_W1T,
                                                           tf1w, wsF + WS_W2T);
  lif_fused<<<Bc, 512, 0, stream>>>(data,
                                    wsI + WS_ROFF_S, (const int2*)(wsI + WS_EDGE_S),
                                    wsI + WS_ROFF_T, (const int2*)(wsI + WS_EDGE_T),
                                    c1w, c1b, c2w, c2b,
                                    wsF + WS_W1T, f1b, wsF + WS_W2T, tf1b,
                                    out);
}